// Round 1
// baseline (65.571 us; speedup 1.0000x reference)
//
#include <hip/hip_runtime.h>
#include <math.h>

// QuantumClassifier: 4 qubits, 2 layers, BATCH=262144.
// State = 16 complex amplitudes per sample -> 32 floats in registers/thread.

// d_ws layout: [2 layers][4 wires][4 floats] = (cos(wy/2), sin(wy/2), cos(wz/2), -sin(wz/2))
__global__ void qc_precompute(const float* __restrict__ w, float* __restrict__ wt) {
    int i = threadIdx.x;  // 0..7 = layer*4 + wire
    if (i < 8) {
        float ty = 0.5f * w[i * 2 + 0];
        float tz = 0.5f * w[i * 2 + 1];
        float cy, sy, cz, sz;
        sincosf(ty, &sy, &cy);
        sincosf(tz, &sz, &cz);
        wt[i * 4 + 0] = cy;
        wt[i * 4 + 1] = sy;
        wt[i * 4 + 2] = cz;   // Re exp(-i tz)
        wt[i * 4 + 3] = -sz;  // Im exp(-i tz)
    }
}

template <bool PRE>
__global__ __launch_bounds__(256) void qc_main(const float* __restrict__ x,
                                               const float* __restrict__ wsrc,
                                               float* __restrict__ out, int B) {
    int b = blockIdx.x * blockDim.x + threadIdx.x;
    if (b >= B) return;

    // Weight-derived trig (uniform across batch).
    float wt[32];
    if (PRE) {
#pragma unroll
        for (int i = 0; i < 32; ++i) wt[i] = wsrc[i];
    } else {
        // Fallback: compute from raw weights per-thread (ws too small).
#pragma unroll
        for (int i = 0; i < 8; ++i) {
            float ty = 0.5f * wsrc[i * 2 + 0];
            float tz = 0.5f * wsrc[i * 2 + 1];
            float cy, sy, cz, sz;
            sincosf(ty, &sy, &cy);
            sincosf(tz, &sz, &cz);
            wt[i * 4 + 0] = cy;
            wt[i * 4 + 1] = sy;
            wt[i * 4 + 2] = cz;
            wt[i * 4 + 3] = -sz;
        }
    }

    // Per-sample data-encoding angles.
    float4 xv = reinterpret_cast<const float4*>(x)[b];
    float cx[4], sx[4];
    sincosf(0.5f * xv.x, &sx[0], &cx[0]);
    sincosf(0.5f * xv.y, &sx[1], &cx[1]);
    sincosf(0.5f * xv.z, &sx[2], &cx[2]);
    sincosf(0.5f * xv.w, &sx[3], &cx[3]);

    // Product state after RY(x_i) on |0...0>. Wire q maps to bit (3-q):
    // flat idx = b0*8 + b1*4 + b2*2 + b3.
    float ar[16], ai[16];
#pragma unroll
    for (int idx = 0; idx < 16; ++idx) {
        float v = 1.0f;
#pragma unroll
        for (int q = 0; q < 4; ++q) {
            int bit = (idx >> (3 - q)) & 1;
            v *= bit ? sx[q] : cx[q];
        }
        ar[idx] = v;
        ai[idx] = 0.0f;
    }

#pragma unroll
    for (int layer = 0; layer < 2; ++layer) {
        // Per-wire RY then RZ (fused).
#pragma unroll
        for (int q = 0; q < 4; ++q) {
            const int base = (layer * 4 + q) * 4;
            const float cy = wt[base + 0], sy = wt[base + 1];
            const float pr = wt[base + 2], pi = wt[base + 3];  // exp(-i tz/...) = pr + i*pi
            const int m = 8 >> q;  // mask of wire q's bit
#pragma unroll
            for (int idx = 0; idx < 16; ++idx) {
                if ((idx & m) == 0) {
                    const int i0 = idx, i1 = idx | m;
                    float a0r = ar[i0], a0i = ai[i0];
                    float a1r = ar[i1], a1i = ai[i1];
                    // RY
                    float n0r = cy * a0r - sy * a1r;
                    float n0i = cy * a0i - sy * a1i;
                    float n1r = sy * a0r + cy * a1r;
                    float n1i = sy * a0i + cy * a1i;
                    // RZ: a0 *= (pr + i pi); a1 *= conj = (pr - i pi)
                    ar[i0] = pr * n0r - pi * n0i;
                    ai[i0] = pr * n0i + pi * n0r;
                    ar[i1] = pr * n1r + pi * n1i;
                    ai[i1] = pr * n1i - pi * n1r;
                }
            }
        }
        // CNOT ring: (0,1),(1,2),(2,3),(3,0). Pure register permutation.
#pragma unroll
        for (int k = 0; k < 4; ++k) {
            const int ctrl = k, tgt = (k + 1) & 3;
            const int cm = 8 >> ctrl, tm = 8 >> tgt;
#pragma unroll
            for (int idx = 0; idx < 16; ++idx) {
                if ((idx & cm) && !(idx & tm)) {
                    const int j = idx | tm;
                    float tr = ar[idx]; ar[idx] = ar[j]; ar[j] = tr;
                    float ti = ai[idx]; ai[idx] = ai[j]; ai[j] = ti;
                }
            }
        }
    }

    // <Z_0>: wire 0 is bit 8 of the flat index.
    float e = 0.0f;
#pragma unroll
    for (int idx = 0; idx < 16; ++idx) {
        float p = ar[idx] * ar[idx] + ai[idx] * ai[idx];
        e += (idx & 8) ? -p : p;
    }
    out[b] = e;
}

extern "C" void kernel_launch(void* const* d_in, const int* in_sizes, int n_in,
                              void* d_out, int out_size, void* d_ws, size_t ws_size,
                              hipStream_t stream) {
    const float* x = (const float*)d_in[0];        // [B,4]
    const float* w = (const float*)d_in[1];        // [2,4,2]
    float* out = (float*)d_out;                    // [B,1]
    const int B = in_sizes[0] / 4;
    const int threads = 256;
    const int blocks = (B + threads - 1) / threads;

    if (ws_size >= 32 * sizeof(float)) {
        float* wt = (float*)d_ws;
        qc_precompute<<<1, 64, 0, stream>>>(w, wt);
        qc_main<true><<<blocks, threads, 0, stream>>>(x, wt, out, B);
    } else {
        qc_main<false><<<blocks, threads, 0, stream>>>(x, w, out, B);
    }
}

// Round 2
// 62.759 us; speedup vs baseline: 1.0448x; 1.0448x over previous
//
#include <hip/hip_runtime.h>
#include <math.h>

// QuantumClassifier: 4 qubits, 2 layers, BATCH=262144.
// Single fused kernel: state = 16 complex amplitudes per sample, fully in
// registers; CNOTs are compile-time register renames; weight trig is uniform
// (compiler emits s_load for w) and costs 8 native sincos per thread.

__global__ __launch_bounds__(256) void qc_main(const float* __restrict__ x,
                                               const float* __restrict__ w,
                                               float* __restrict__ out, int B) {
    int b = blockIdx.x * blockDim.x + threadIdx.x;
    if (b >= B) return;

    // Batch-uniform weight trig: gate i = (layer*4 + wire).
    // RY half-angle -> (cy, sy); RZ half-angle phase exp(-i t/2) -> (pr, pi).
    float cy[8], sy[8], pr[8], pi[8];
#pragma unroll
    for (int i = 0; i < 8; ++i) {
        float s0, c0, s1, c1;
        __sincosf(0.5f * w[2 * i + 0], &s0, &c0);
        __sincosf(0.5f * w[2 * i + 1], &s1, &c1);
        cy[i] = c0; sy[i] = s0;
        pr[i] = c1; pi[i] = -s1;
    }

    // Per-sample data-encoding angles (args in [0, 0.5) -> native sin/cos fine).
    float4 xv = reinterpret_cast<const float4*>(x)[b];
    float cx[4], sx[4];
    __sincosf(0.5f * xv.x, &sx[0], &cx[0]);
    __sincosf(0.5f * xv.y, &sx[1], &cx[1]);
    __sincosf(0.5f * xv.z, &sx[2], &cx[2]);
    __sincosf(0.5f * xv.w, &sx[3], &cx[3]);

    // Product state after RY(x_i)|0>: amp(idx) = prod_q (bit ? s : c).
    // Wire q lives at bit (3-q): idx = b0*8 + b1*4 + b2*2 + b3.
    // Outer-product tree: 4 + 4 + 16 = 24 mults.
    float v01[4], v23[4];
    v01[0] = cx[0] * cx[1]; v01[1] = cx[0] * sx[1];
    v01[2] = sx[0] * cx[1]; v01[3] = sx[0] * sx[1];
    v23[0] = cx[2] * cx[3]; v23[1] = cx[2] * sx[3];
    v23[2] = sx[2] * cx[3]; v23[3] = sx[2] * sx[3];

    float ar[16], ai[16];
#pragma unroll
    for (int idx = 0; idx < 16; ++idx) {
        ar[idx] = v01[idx >> 2] * v23[idx & 3];
        ai[idx] = 0.0f;  // compiler folds zeros through the first gates
    }

#pragma unroll
    for (int layer = 0; layer < 2; ++layer) {
        // Per-wire fused RY then RZ.
#pragma unroll
        for (int q = 0; q < 4; ++q) {
            const int g = layer * 4 + q;
            const float c = cy[g], s = sy[g];
            const float zr = pr[g], zi = pi[g];  // exp(-i tz/2)
            const int m = 8 >> q;
#pragma unroll
            for (int idx = 0; idx < 16; ++idx) {
                if ((idx & m) == 0) {
                    const int i0 = idx, i1 = idx | m;
                    float a0r = ar[i0], a0i = ai[i0];
                    float a1r = ar[i1], a1i = ai[i1];
                    // RY
                    float n0r = c * a0r - s * a1r;
                    float n0i = c * a0i - s * a1i;
                    float n1r = s * a0r + c * a1r;
                    float n1i = s * a0i + c * a1i;
                    // RZ: a0 *= (zr + i zi); a1 *= (zr - i zi)
                    ar[i0] = zr * n0r - zi * n0i;
                    ai[i0] = zr * n0i + zi * n0r;
                    ar[i1] = zr * n1r + zi * n1i;
                    ai[i1] = zr * n1i - zi * n1r;
                }
            }
        }
        // CNOT ring (0,1),(1,2),(2,3),(3,0): register permutation, free.
#pragma unroll
        for (int k = 0; k < 4; ++k) {
            const int ctrl = k, tgt = (k + 1) & 3;
            const int cm = 8 >> ctrl, tm = 8 >> tgt;
#pragma unroll
            for (int idx = 0; idx < 16; ++idx) {
                if ((idx & cm) && !(idx & tm)) {
                    const int j = idx | tm;
                    float tr = ar[idx]; ar[idx] = ar[j]; ar[j] = tr;
                    float ti = ai[idx]; ai[idx] = ai[j]; ai[j] = ti;
                }
            }
        }
    }

    // <Z_0>: wire 0 is bit 8.
    float e = 0.0f;
#pragma unroll
    for (int idx = 0; idx < 16; ++idx) {
        float p = ar[idx] * ar[idx] + ai[idx] * ai[idx];
        e += (idx & 8) ? -p : p;
    }
    out[b] = e;
}

extern "C" void kernel_launch(void* const* d_in, const int* in_sizes, int n_in,
                              void* d_out, int out_size, void* d_ws, size_t ws_size,
                              hipStream_t stream) {
    const float* x = (const float*)d_in[0];  // [B,4]
    const float* w = (const float*)d_in[1];  // [2,4,2]
    float* out = (float*)d_out;              // [B,1]
    const int B = in_sizes[0] / 4;
    const int threads = 256;
    const int blocks = (B + threads - 1) / threads;
    qc_main<<<blocks, threads, 0, stream>>>(x, w, out, B);
}

// Round 3
// 57.569 us; speedup vs baseline: 1.1390x; 1.0902x over previous
//
#include <hip/hip_runtime.h>
#include <math.h>

// QuantumClassifier: 4 qubits, 2 layers, BATCH=262144.
//
// Heisenberg-picture reduction (verified algebra):
//   <Z0> = <psi2| I (x) A1 (x) A2 (x) A3 |psi2>
// where
//   - psi2 = Ring1 * prod_q f_q,  f_q = (cos t_q, sin t_q * e^{i b_q})
//       t_q = (x_q + w[0][q][0])/2   (data RY and layer-1 RY fuse: same axis)
//       b_q = w[0][q][1]             (layer-1 RZ, full angle, global phase dropped)
//   - Ring1 = CNOT(0,1)(1,2)(2,3)(3,0): a pure basis permutation (free renames)
//   - A_q = [[cos a, -sin a], [-sin a, -cos a]], a = w[1][q][0] full angle
//       (layer-2 RZs commute with Z1Z2Z3; wire-0 layer-2 gates hit the identity
//        factor; final CNOT ring pulls Z0 back to Z1Z2Z3.)
// Weights w[1][*][1] and w[1][0][0] provably do not affect the output.

__global__ __launch_bounds__(256) void qc_main(const float* __restrict__ x,
                                               const float* __restrict__ w,
                                               float* __restrict__ out, int B) {
    int b = blockIdx.x * blockDim.x + threadIdx.x;
    if (b >= B) return;

    float4 xv = reinterpret_cast<const float4*>(x)[b];
    float xs[4] = {xv.x, xv.y, xv.z, xv.w};

    // Per-qubit factor vectors f_q[0] = (C,0), f_q[1] = S * e^{i b}.
    float fr[4][2], fi[4][2];
#pragma unroll
    for (int q = 0; q < 4; ++q) {
        float Cq, Sq, gr, gi;
        __sincosf(0.5f * (xs[q] + w[2 * q]), &Sq, &Cq);  // fused RY half-angle
        __sincosf(w[2 * q + 1], &gi, &gr);               // RZ full-angle phase
        fr[q][0] = Cq;       fi[q][0] = 0.0f;
        fr[q][1] = Sq * gr;  fi[q][1] = Sq * gi;
    }

    // Tensor product: wire q lives at bit (3-q); idx = b0*8 + b1*4 + b2*2 + b3.
    float t01r[4], t01i[4], t23r[4], t23i[4];
#pragma unroll
    for (int p = 0; p < 4; ++p) {
        const int hb = p >> 1, lb = p & 1;
        t01r[p] = fr[0][hb] * fr[1][lb] - fi[0][hb] * fi[1][lb];
        t01i[p] = fr[0][hb] * fi[1][lb] + fi[0][hb] * fr[1][lb];
        t23r[p] = fr[2][hb] * fr[3][lb] - fi[2][hb] * fi[3][lb];
        t23i[p] = fr[2][hb] * fi[3][lb] + fi[2][hb] * fr[3][lb];
    }
    float ar[16], ai[16];
#pragma unroll
    for (int idx = 0; idx < 16; ++idx) {
        const int p = idx >> 2, r = idx & 3;
        ar[idx] = t01r[p] * t23r[r] - t01i[p] * t23i[r];
        ai[idx] = t01r[p] * t23i[r] + t01i[p] * t23r[r];
    }

    // First CNOT ring (0,1),(1,2),(2,3),(3,0): compile-time register renames.
#pragma unroll
    for (int k = 0; k < 4; ++k) {
        const int cm = 8 >> k, tm = 8 >> ((k + 1) & 3);
#pragma unroll
        for (int idx = 0; idx < 16; ++idx) {
            if ((idx & cm) && !(idx & tm)) {
                const int j = idx | tm;
                float tr = ar[idx]; ar[idx] = ar[j]; ar[j] = tr;
                float ti = ai[idx]; ai[idx] = ai[j]; ai[j] = ti;
            }
        }
    }

    // z = (A1 (x) A2 (x) A3) psi2, applied wire-by-wire (wires 1,2,3).
    float zr[16], zi[16];
#pragma unroll
    for (int idx = 0; idx < 16; ++idx) { zr[idx] = ar[idx]; zi[idx] = ai[idx]; }
#pragma unroll
    for (int q = 1; q < 4; ++q) {
        float sa, ca;
        __sincosf(w[8 + 2 * q], &sa, &ca);  // layer-2 RY full angle, wires 1..3
        const int m = 8 >> q;
#pragma unroll
        for (int idx = 0; idx < 16; ++idx) {
            if ((idx & m) == 0) {
                const int i1 = idx | m;
                float v0r = zr[idx], v0i = zi[idx];
                float v1r = zr[i1], v1i = zi[i1];
                zr[idx] = ca * v0r - sa * v1r;
                zi[idx] = ca * v0i - sa * v1i;
                zr[i1] = -sa * v0r - ca * v1r;
                zi[i1] = -sa * v0i - ca * v1i;
            }
        }
    }

    // expz = Re <psi2, z>
    float e = 0.0f;
#pragma unroll
    for (int idx = 0; idx < 16; ++idx) e += ar[idx] * zr[idx] + ai[idx] * zi[idx];
    out[b] = e;
}

extern "C" void kernel_launch(void* const* d_in, const int* in_sizes, int n_in,
                              void* d_out, int out_size, void* d_ws, size_t ws_size,
                              hipStream_t stream) {
    const float* x = (const float*)d_in[0];  // [B,4]
    const float* w = (const float*)d_in[1];  // [2,4,2]
    float* out = (float*)d_out;              // [B,1]
    const int B = in_sizes[0] / 4;
    const int threads = 256;
    const int blocks = (B + threads - 1) / threads;
    qc_main<<<blocks, threads, 0, stream>>>(x, w, out, B);
}

// Round 4
// 55.509 us; speedup vs baseline: 1.1813x; 1.0371x over previous
//
#include <hip/hip_runtime.h>
#include <math.h>

// QuantumClassifier: 4 qubits, 2 layers, BATCH=262144 — fully closed form.
//
// Heisenberg picture, both CNOT rings conjugated through to the input
// product state. Observable = sum of 8 Pauli strings; expectation of a
// Pauli string on a product state factorizes:
//   <Z_q> = cos(th_q), <X_q> = sin(th_q) cos(b_q), <Y_q> = sin(th_q) sin(b_q)
// with th_q = x_q + w[0][q][0] (data RY and layer-1 RY fuse; full angle),
// b_q = w[0][q][1]. Layer-2 terms give per-string coefficients from
// a_q = w[1][q][0] (q=1..3); w[1][*][1] and w[1][0][0] drop out.
//
//   e = K1*C0*C1*C3 + K2*S0*S1*C2*S3 + K3*S2*S3 + K4*S0*S1*S2
//     + K5*S1*S2*C3 + K6*S0*C1*S2*S3 + K7*C0*S1*C2*S3 + K8*S0
// (Cq=cos th_q, Sq=sin th_q; K's are batch-uniform, see below.)

__global__ __launch_bounds__(256) void qc_main(const float* __restrict__ x,
                                               const float* __restrict__ w,
                                               float* __restrict__ out, int B) {
    int b = blockIdx.x * blockDim.x + threadIdx.x;
    if (b >= B) return;

    float4 xv = reinterpret_cast<const float4*>(x)[b];  // issue load early

    // ---- batch-uniform constants (scalar loads of w; ~55 VALU instr) ----
    float CB[4], SB[4];           // cos/sin of layer-1 RZ full angles b_q
#pragma unroll
    for (int q = 0; q < 4; ++q) __sincosf(w[2 * q + 1], &SB[q], &CB[q]);
    float c[4], s[4];             // cos/sin of layer-2 RY full angles a_q, q=1..3
#pragma unroll
    for (int q = 1; q < 4; ++q) __sincosf(w[8 + 2 * q], &s[q], &c[q]);

    const float K1 =  c[1] * c[2] * c[3];                       // Z0 Z1 Z3
    const float K2 = -c[1] * c[2] * s[3] * CB[0] * CB[1] * CB[3]; // X0 X1 Z2 X3
    const float K3 =  c[1] * s[2] * c[3] * SB[2] * SB[3];         // Y2 Y3
    const float K4 = -c[1] * s[2] * s[3] * SB[0] * SB[1] * CB[2]; // Y0 Y1 X2
    const float K5 = -s[1] * c[2] * c[3] * CB[1] * CB[2];         // X1 X2 Z3
    const float K6 = -s[1] * c[2] * s[3] * SB[0] * SB[2] * CB[3]; // Y0 Z1 Y2 X3
    const float K7 = -s[1] * s[2] * c[3] * SB[1] * SB[3];         // Z0 Y1 Z2 Y3
    const float K8 = -s[1] * s[2] * s[3] * CB[0];                 // X0

    // ---- per-sample: th_q = x_q + w[0][q][0], 4 native sincos ----
    float S0, C0, S1, C1, S2, C2, S3, C3;
    __sincosf(xv.x + w[0], &S0, &C0);
    __sincosf(xv.y + w[2], &S1, &C1);
    __sincosf(xv.z + w[4], &S2, &C2);
    __sincosf(xv.w + w[6], &S3, &C3);

    const float p01 = S0 * S1, p23 = S2 * S3, c2s3 = C2 * S3;
    float e = K1 * (C0 * C1 * C3);
    e = fmaf(K2, p01 * c2s3, e);
    e = fmaf(K3, p23, e);
    e = fmaf(K4, p01 * S2, e);
    e = fmaf(K5, S1 * S2 * C3, e);
    e = fmaf(K6, S0 * C1 * p23, e);
    e = fmaf(K7, C0 * S1 * c2s3, e);
    e = fmaf(K8, S0, e);
    out[b] = e;
}

extern "C" void kernel_launch(void* const* d_in, const int* in_sizes, int n_in,
                              void* d_out, int out_size, void* d_ws, size_t ws_size,
                              hipStream_t stream) {
    const float* x = (const float*)d_in[0];  // [B,4]
    const float* w = (const float*)d_in[1];  // [2,4,2]
    float* out = (float*)d_out;              // [B,1]
    const int B = in_sizes[0] / 4;
    const int threads = 256;
    const int blocks = (B + threads - 1) / threads;
    qc_main<<<blocks, threads, 0, stream>>>(x, w, out, B);
}